// Round 7
// baseline (39.107 us; speedup 1.0000x reference)
//
#include <hip/hip_runtime.h>
#include <math.h>

#define POOL 7
#define CCH 256   // channels
#define CANON 224.0f
#define MAX_LDS_KEYS 4096

typedef float nfloat4 __attribute__((ext_vector_type(4)));

// ---- level selection, replicating reference f32 math exactly ----
__device__ __forceinline__ int roi_level_of(const float* __restrict__ rois,
                                            const float* __restrict__ metas,
                                            int i, int N) {
    const int b = i / N;
    const float* box = rois + (size_t)i * 4;
    const float h = box[2] - box[0];
    const float w = box[3] - box[1];
    const float pad_h = metas[b * 11 + 7];
    const float pad_w = metas[b * 11 + 8];
    const float area = pad_h * pad_w;
    const float lvlf = logf(sqrtf(h * w) / (CANON / sqrtf(area))) / logf(2.0f);
    int lvl = 4 + (int)rintf(lvlf);
    return lvl < 2 ? 2 : (lvl > 5 ? 5 : lvl);
}

__device__ __forceinline__ int bucket_key(const float* __restrict__ rois,
                                          const float* __restrict__ metas,
                                          int i, int N, int* lvl_out) {
    const int lvl = roi_level_of(rois, metas, i, N);
    *lvl_out = lvl;
    const float yc = 0.5f * (rois[(size_t)i * 4 + 0] + rois[(size_t)i * 4 + 2]);
    int band = (int)(yc * 16.0f); band = band < 0 ? 0 : (band > 15 ? 15 : band);
    const int b = i / N;
    return ((b & 1) * 64) + (lvl - 2) * 16 + band;   // 0..127
}

// Single-block counting sort into 128 buckets (image&1 x level x y-band16).
// Keys cached in LDS; scan done by ONE wave via shfl (3 block barriers total).
// Intra-bucket order is atomics-nondeterministic, but each ROI writes a
// private output slice, so the final output is order-independent.
__global__ __launch_bounds__(1024) void bucket_kernel(
    const float* __restrict__ rois, const float* __restrict__ metas,
    int B, int N, int* __restrict__ perm)
{
    __shared__ int counts[128];
    __shared__ int offs[128];
    __shared__ unsigned short keys[MAX_LDS_KEYS];
    const int total = B * N;
    const int tid = threadIdx.x;
    const bool cache = (total <= MAX_LDS_KEYS);

    if (tid < 128) counts[tid] = 0;
    __syncthreads();

    for (int i = tid; i < total; i += 1024) {
        int lvl;
        const int key = bucket_key(rois, metas, i, N, &lvl);
        if (cache) keys[i] = (unsigned short)(key | (lvl << 8));
        atomicAdd(&counts[key], 1);
    }
    __syncthreads();

    // 128-bucket exclusive scan by wave 0: lane l owns buckets 2l, 2l+1.
    if (tid < 64) {
        const int c0 = counts[2 * tid], c1 = counts[2 * tid + 1];
        const int s = c0 + c1;
        int incl = s;
#pragma unroll
        for (int d = 1; d < 64; d <<= 1) {
            const int v = __shfl_up(incl, d, 64);
            if (tid >= d) incl += v;
        }
        const int excl = incl - s;
        offs[2 * tid]     = excl;
        offs[2 * tid + 1] = excl + c0;
    }
    __syncthreads();

    for (int i = tid; i < total; i += 1024) {
        int key, lvl;
        if (cache) { const int e = keys[i]; key = e & 0xFF; lvl = e >> 8; }
        else       { key = bucket_key(rois, metas, i, N, &lvl); }
        const int pos = atomicAdd(&offs[key], 1);
        perm[pos] = i | (lvl << 24);
    }
}

// 7 waves x 7 points: wave = output row (y-math hoisted), 7 x-samples each.
__device__ __forceinline__ void process_roi(
    int e,
    const float* __restrict__ rois,
    const float* __restrict__ fm2, const float* __restrict__ fm3,
    const float* __restrict__ fm4, const float* __restrict__ fm5,
    float* __restrict__ out, int N, int wave, int lane)
{
    const int idx = e & 0xFFFFFF;          // b*N + n
    const int lvl = e >> 24;
    const int b = idx / N;

    const float* box = rois + (size_t)idx * 4;
    const float y1 = box[0], x1 = box[1], y2 = box[2], x2 = box[3];
    const float h = y2 - y1;
    const float w = x2 - x1;

    const float* fm;
    int H, W;
    if (lvl == 2)      { fm = fm2; H = 256; W = 256; }
    else if (lvl == 3) { fm = fm3; H = 128; W = 128; }
    else if (lvl == 4) { fm = fm4; H = 64;  W = 64;  }
    else               { fm = fm5; H = 32;  W = 32;  }
    const float* img = fm + (size_t)b * H * W * CCH;

    const float Hm1 = (float)(H - 1);
    const float Wm1 = (float)(W - 1);

    // y-side bilinear (one row per wave)
    const float ii = (float)wave / 6.0f;
    const float ys = (y1 + ii * h) * Hm1;
    const float y0f = floorf(ys);
    const float wy = ys - y0f;
    int y0 = (int)y0f; y0 = y0 < 0 ? 0 : (y0 > H - 1 ? H - 1 : y0);
    int y1i = y0 + 1;  y1i = y1i > H - 1 ? H - 1 : y1i;

    const nfloat4* rowT = (const nfloat4*)(img + (size_t)y0  * W * CCH) + lane;
    const nfloat4* rowB = (const nfloat4*)(img + (size_t)y1i * W * CCH) + lane;
    nfloat4* outp = (nfloat4*)(out + (size_t)idx * (POOL * POOL * CCH))
                    + wave * (POOL * 64) + lane;

#pragma unroll
    for (int j = 0; j < POOL; ++j) {
        const float jj = (float)j / 6.0f;
        const float xs = (x1 + jj * w) * Wm1;
        const float x0f = floorf(xs);
        const float wx = xs - x0f;
        int x0 = (int)x0f; x0 = x0 < 0 ? 0 : (x0 > W - 1 ? W - 1 : x0);
        int x1i = x0 + 1;  x1i = x1i > W - 1 ? W - 1 : x1i;

        const nfloat4 vtl = rowT[(size_t)x0  * 64];
        const nfloat4 vtr = rowT[(size_t)x1i * 64];
        const nfloat4 vbl = rowB[(size_t)x0  * 64];
        const nfloat4 vbr = rowB[(size_t)x1i * 64];

        const nfloat4 top = vtl + (vtr - vtl) * wx;
        const nfloat4 bot = vbl + (vbr - vbl) * wx;
        const nfloat4 res = top + (bot - top) * wy;

        __builtin_nontemporal_store(res, outp + j * 64);
    }
}

// Each block handles 2 consecutive sorted ROIs -> 1000 blocks = one residency
// round (4 blocks/CU at 7 waves), better tail + L1 reuse within a y-band.
__global__ __launch_bounds__(448) void roi_align_kernel(
    const float* __restrict__ rois,
    const float* __restrict__ fm2, const float* __restrict__ fm3,
    const float* __restrict__ fm4, const float* __restrict__ fm5,
    const int* __restrict__ perm,
    float* __restrict__ out, int B, int N)
{
    const int total = B * N;
    const int npair = (total + 1) >> 1;
    // Bijective inverse round-robin XCD mapping over pair indices: block b
    // runs on XCD (b&7); give that XCD a contiguous chunk of sorted pairs.
    const int q = npair >> 3, r = npair & 7;
    const int k = blockIdx.x & 7, jb = blockIdx.x >> 3;
    const int pp = (k < r) ? k * (q + 1) + jb : r * (q + 1) + (k - r) * q + jb;

    const int wave = threadIdx.x >> 6;     // 0..6 = output row
    const int lane = threadIdx.x & 63;     // 4 channels each

    const int p0 = pp * 2;
    process_roi(perm[p0], rois, fm2, fm3, fm4, fm5, out, N, wave, lane);
    if (p0 + 1 < total)
        process_roi(perm[p0 + 1], rois, fm2, fm3, fm4, fm5, out, N, wave, lane);
}

extern "C" void kernel_launch(void* const* d_in, const int* in_sizes, int n_in,
                              void* d_out, int out_size, void* d_ws, size_t ws_size,
                              hipStream_t stream) {
    const float* rois  = (const float*)d_in[0];
    const float* metas = (const float*)d_in[1];
    const float* fm2   = (const float*)d_in[2];
    const float* fm3   = (const float*)d_in[3];
    const float* fm4   = (const float*)d_in[4];
    const float* fm5   = (const float*)d_in[5];
    float* out = (float*)d_out;
    int* perm = (int*)d_ws;

    const int B = in_sizes[1] / 11;          // img_metas: [B,11]
    const int N = in_sizes[0] / (4 * B);     // rois: [B,N,4]
    const int total = B * N;
    const int npair = (total + 1) >> 1;

    bucket_kernel<<<1, 1024, 0, stream>>>(rois, metas, B, N, perm);
    roi_align_kernel<<<npair, 448, 0, stream>>>(rois, fm2, fm3, fm4, fm5,
                                                perm, out, B, N);
}